// Round 1
// baseline (1171.417 us; speedup 1.0000x reference)
//
#include <hip/hip_runtime.h>
#include <math.h>

#define BB 4096
#define CC 32
#define TT 512
#define NOUTC 16
#define NCLSC 4
#define EPSF 1e-5f

// ws layout (floats):
// 0: scale1[32]   32: shift1[32]   64: scale2[32]   96: shift2[32]
// 128: hT[32][4096]          (131072)
// 131200: part[64][4096]     (262144)   total 393344 floats = 1.58 MB

// ---------------- kernel 1: BN1 stats (per-sample block, partials) ----------------
__global__ __launch_bounds__(512) void k1_stats(const float* __restrict__ de,
    const float* __restrict__ dw, const float* __restrict__ db,
    const float* __restrict__ pw, const float* __restrict__ pwb,
    float* __restrict__ part) {
  __shared__ __align__(16) float s1[CC * 514];
  __shared__ float red16[CC * 16];
  int b = blockIdx.x, tid = threadIdx.x;
  const float* deb = de + (size_t)b * CC * TT;
  for (int i = tid; i < CC * 514; i += 512) {
    int c = i / 514, t = i - c * 514 - 1;
    s1[i] = (t >= 0 && t < TT) ? deb[c * TT + t] : 0.f;
  }
  __syncthreads();
  float xx[CC];
  {
    float x1[CC];
#pragma unroll
    for (int c = 0; c < CC; c++) {
      float l = s1[c * 514 + tid];
      float m = s1[c * 514 + tid + 1];
      float r = s1[c * 514 + tid + 2];
      x1[c] = fmaf(dw[c * 3 + 0], l, fmaf(dw[c * 3 + 1], m, fmaf(dw[c * 3 + 2], r, db[c])));
    }
#pragma unroll
    for (int o = 0; o < CC; o++) {
      float acc = pwb[o];
#pragma unroll
      for (int c = 0; c < CC; c++) acc = fmaf(pw[o * CC + c], x1[c], acc);
      xx[o] = acc;
    }
  }
  // ---- sum pass ----
  __syncthreads();
#pragma unroll
  for (int o = 0; o < CC; o++) s1[o * 514 + tid] = xx[o];
  __syncthreads();
  {
    int c = tid >> 4, j = tid & 15;
    float p = 0;
#pragma unroll
    for (int t = 0; t < 32; t++) p += s1[c * 514 + j * 32 + t];
    red16[c * 16 + j] = p;
  }
  __syncthreads();
  if (tid < CC) {
    float s = 0;
#pragma unroll
    for (int j = 0; j < 16; j++) s += red16[tid * 16 + j];
    part[(size_t)tid * BB + b] = s;
  }
  // ---- sumsq pass ----
  __syncthreads();
#pragma unroll
  for (int o = 0; o < CC; o++) s1[o * 514 + tid] = xx[o] * xx[o];
  __syncthreads();
  {
    int c = tid >> 4, j = tid & 15;
    float p = 0;
#pragma unroll
    for (int t = 0; t < 32; t++) p += s1[c * 514 + j * 32 + t];
    red16[c * 16 + j] = p;
  }
  __syncthreads();
  if (tid < CC) {
    float s = 0;
#pragma unroll
    for (int j = 0; j < 16; j++) s += red16[tid * 16 + j];
    part[(size_t)(CC + tid) * BB + b] = s;
  }
}

// ---------------- kernel 2: finalize BN1 scale/shift ----------------
__global__ void k2_bn1(const float* __restrict__ part, const float* __restrict__ g,
                       const float* __restrict__ bta, float* __restrict__ ws) {
  __shared__ float redS[256], redQ[256];
  int o = blockIdx.x, tid = threadIdx.x;
  const float* ps = part + (size_t)o * BB;
  const float* pq = part + (size_t)(CC + o) * BB;
  float s = 0, q = 0;
  for (int i = tid; i < BB; i += 256) { s += ps[i]; q += pq[i]; }
  redS[tid] = s; redQ[tid] = q;
  __syncthreads();
  for (int k = 128; k > 0; k >>= 1) {
    if (tid < k) { redS[tid] += redS[tid + k]; redQ[tid] += redQ[tid + k]; }
    __syncthreads();
  }
  if (tid == 0) {
    float N = (float)BB * (float)TT;
    float mean = redS[0] / N;
    float var = redQ[0] / N - mean * mean;
    float sc = g[o] / sqrtf(var + EPSF);
    ws[o] = sc;
    ws[32 + o] = bta[o] - mean * sc;
  }
}

// ---------------- kernel 3: per-sample main pipeline ----------------
__global__ __launch_bounds__(512) void k3_main(const float* __restrict__ de,
    const float* __restrict__ dw, const float* __restrict__ db,
    const float* __restrict__ pw, const float* __restrict__ pwb,
    const float* __restrict__ ws,       // scale1 @0, shift1 @32
    const float* __restrict__ gcw,      // [512][16]
    const float* __restrict__ fcw,      // [512][32]
    const float* __restrict__ fcb,
    float* __restrict__ hT) {
  __shared__ __align__(16) float x_s[CC * 516];   // post-BN relu'd x, padded stride
  __shared__ __align__(16) float buf0[CC * 514];  // de staging; later gcT[16][516]
  __shared__ float num_s[CC * 33];
  __shared__ float mu_s[CC], inv_s[CC];
  __shared__ float red16[CC * 16];
  __shared__ float Z_s[CC * NOUTC];
  __shared__ float g2_s[CC * NOUTC];
  __shared__ float red2[CC * 16];

  int b = blockIdx.x, tid = threadIdx.x;
  const float* deb = de + (size_t)b * CC * TT;
  for (int i = tid; i < CC * 514; i += 512) {
    int c = i / 514, t = i - c * 514 - 1;
    buf0[i] = (t >= 0 && t < TT) ? deb[c * TT + t] : 0.f;
  }
  __syncthreads();
  // depthwise + pointwise + BN1 + relu, one t-column per thread
  {
    float x1[CC];
#pragma unroll
    for (int c = 0; c < CC; c++) {
      float l = buf0[c * 514 + tid];
      float m = buf0[c * 514 + tid + 1];
      float r = buf0[c * 514 + tid + 2];
      x1[c] = fmaf(dw[c * 3 + 0], l, fmaf(dw[c * 3 + 1], m, fmaf(dw[c * 3 + 2], r, db[c])));
    }
#pragma unroll
    for (int o = 0; o < CC; o++) {
      float acc = pwb[o];
#pragma unroll
      for (int c = 0; c < CC; c++) acc = fmaf(pw[o * CC + c], x1[c], acc);
      float xv = fmaf(acc, ws[o], ws[32 + o]);
      x_s[o * 516 + tid] = fmaxf(xv, 0.f);
    }
  }
  __syncthreads();
  // stage gc_w transposed into buf0 (de is dead) + mu partials, concurrently
  for (int i = tid; i < TT * NOUTC; i += 512) {
    int t = i >> 4, o = i & 15;
    buf0[o * 516 + t] = gcw[i];
  }
  {
    int c = tid >> 4, j = tid & 15;
    const float4* xr = reinterpret_cast<const float4*>(x_s + c * 516 + j * 32);
    float p = 0;
#pragma unroll
    for (int q = 0; q < 8; q++) { float4 v = xr[q]; p += (v.x + v.y) + (v.z + v.w); }
    red16[c * 16 + j] = p;
  }
  __syncthreads();
  if (tid < CC) {
    float s = 0;
#pragma unroll
    for (int j = 0; j < 16; j++) s += red16[tid * 16 + j];
    mu_s[tid] = s * (1.f / (float)TT);
  }
  __syncthreads();
  // Gram: num[n][m] = sum_t x_n x_m - T*mu_n*mu_m  (symmetric pairs)
  for (int p = tid; p < 528; p += 512) {
    int n = 0, r = p;
    while (r >= CC - n) { r -= CC - n; ++n; }
    int m = n + r;
    const float4* xa = reinterpret_cast<const float4*>(x_s + n * 516);
    const float4* xb = reinterpret_cast<const float4*>(x_s + m * 516);
    float ax = 0, ay = 0, az = 0, aw = 0;
    for (int i = 0; i < TT / 4; i++) {
      float4 a = xa[i], c4 = xb[i];
      ax = fmaf(a.x, c4.x, ax); ay = fmaf(a.y, c4.y, ay);
      az = fmaf(a.z, c4.z, az); aw = fmaf(a.w, c4.w, aw);
    }
    float dot = (ax + ay) + (az + aw) - (float)TT * mu_s[n] * mu_s[m];
    num_s[n * 33 + m] = dot;
    num_s[m * 33 + n] = dot;
  }
  __syncthreads();
  if (tid < CC) inv_s[tid] = rsqrtf(num_s[tid * 33 + tid]);
  __syncthreads();
  // Z[n][o] = inv_n * (x @ gc_w)[n][o]
  {
    int n = tid >> 4, o = tid & 15;
    const float4* xa = reinterpret_cast<const float4*>(x_s + n * 516);
    const float4* gt = reinterpret_cast<const float4*>(buf0 + o * 516);
    float ax = 0, ay = 0, az = 0, aw = 0;
    for (int i = 0; i < TT / 4; i++) {
      float4 a = xa[i], g4 = gt[i];
      ax = fmaf(a.x, g4.x, ax); ay = fmaf(a.y, g4.y, ay);
      az = fmaf(a.z, g4.z, az); aw = fmaf(a.w, g4.w, aw);
    }
    Z_s[n * NOUTC + o] = ((ax + ay) + (az + aw)) * inv_s[n];
  }
  __syncthreads();
  // g2[n][o] = relu(inv_n * sum_m num[n][m] * Z[m][o])
  {
    int n = tid >> 4, o = tid & 15;
    float s = 0;
#pragma unroll
    for (int m = 0; m < CC; m++) s = fmaf(num_s[n * 33 + m], Z_s[m * NOUTC + o], s);
    g2_s[n * NOUTC + o] = fmaxf(s * inv_s[n], 0.f);
  }
  __syncthreads();
  // h_pre[j] = fcb[j] + sum_i g2[i] * fcw[i][j]
  {
    int j = tid & 31, ch = tid >> 5;  // ch in 0..15
    float p = 0;
#pragma unroll
    for (int ii = 0; ii < 32; ii++) {
      int i = ch * 32 + ii;
      p = fmaf(g2_s[i], fcw[i * CC + j], p);
    }
    red2[j * 16 + ch] = p;
  }
  __syncthreads();
  if (tid < CC) {
    float h = fcb[tid];
#pragma unroll
    for (int ch = 0; ch < 16; ch++) h += red2[tid * 16 + ch];
    hT[(size_t)tid * BB + b] = h;
  }
}

// ---------------- kernel 4: BN2 stats (one block per feature) ----------------
__global__ void k4_bn2(const float* __restrict__ hT, const float* __restrict__ g,
                       const float* __restrict__ bta, float* __restrict__ ws) {
  __shared__ float redS[256], redQ[256];
  int j = blockIdx.x, tid = threadIdx.x;
  const float* row = hT + (size_t)j * BB;
  float s = 0, q = 0;
  for (int i = tid; i < BB; i += 256) { float v = row[i]; s += v; q = fmaf(v, v, q); }
  redS[tid] = s; redQ[tid] = q;
  __syncthreads();
  for (int k = 128; k > 0; k >>= 1) {
    if (tid < k) { redS[tid] += redS[tid + k]; redQ[tid] += redQ[tid + k]; }
    __syncthreads();
  }
  if (tid == 0) {
    float N = (float)BB;
    float mean = redS[0] / N;
    float var = redQ[0] / N - mean * mean;
    float sc = g[j] / sqrtf(var + EPSF);
    ws[64 + j] = sc;
    ws[96 + j] = bta[j] - mean * sc;
  }
}

// ---------------- kernel 5: BN2 apply + sigmoid + classifier ----------------
__global__ void k5_out(const float* __restrict__ hT, const float* __restrict__ ws,
                       const float* __restrict__ clsw, const float* __restrict__ clsb,
                       float* __restrict__ out) {
  __shared__ float hs[CC * 257];
  int b0 = blockIdx.x * 256, tid = threadIdx.x;
  for (int i = tid; i < CC * 256; i += 256) {
    int j = i >> 8, bb = i & 255;
    float v = fmaf(hT[(size_t)j * BB + b0 + bb], ws[64 + j], ws[96 + j]);
    hs[j * 257 + bb] = 1.f / (1.f + expf(-v));
  }
  __syncthreads();
  float o0 = clsb[0], o1 = clsb[1], o2 = clsb[2], o3 = clsb[3];
#pragma unroll
  for (int j = 0; j < CC; j++) {
    float h = hs[j * 257 + tid];
    o0 = fmaf(h, clsw[j * 4 + 0], o0);
    o1 = fmaf(h, clsw[j * 4 + 1], o1);
    o2 = fmaf(h, clsw[j * 4 + 2], o2);
    o3 = fmaf(h, clsw[j * 4 + 3], o3);
  }
  float4* out4 = reinterpret_cast<float4*>(out);
  out4[b0 + tid] = make_float4(o0, o1, o2, o3);
}

extern "C" void kernel_launch(void* const* d_in, const int* in_sizes, int n_in,
                              void* d_out, int out_size, void* d_ws, size_t ws_size,
                              hipStream_t stream) {
  const float* de   = (const float*)d_in[0];
  // d_in[1] = adj (unused by forward)
  const float* dw   = (const float*)d_in[2];
  const float* db_  = (const float*)d_in[3];
  const float* pw   = (const float*)d_in[4];
  const float* pwb  = (const float*)d_in[5];
  const float* bn1g = (const float*)d_in[6];
  const float* bn1b = (const float*)d_in[7];
  const float* gcw  = (const float*)d_in[8];
  const float* fcw  = (const float*)d_in[9];
  const float* fcb  = (const float*)d_in[10];
  const float* bn2g = (const float*)d_in[11];
  const float* bn2b = (const float*)d_in[12];
  const float* clsw = (const float*)d_in[13];
  const float* clsb = (const float*)d_in[14];

  float* ws   = (float*)d_ws;
  float* hT   = ws + 128;
  float* part = ws + 131200;
  float* out  = (float*)d_out;

  k1_stats<<<BB, 512, 0, stream>>>(de, dw, db_, pw, pwb, part);
  k2_bn1<<<CC, 256, 0, stream>>>(part, bn1g, bn1b, ws);
  k3_main<<<BB, 512, 0, stream>>>(de, dw, db_, pw, pwb, ws, gcw, fcw, fcb, hT);
  k4_bn2<<<CC, 256, 0, stream>>>(hT, bn2g, bn2b, ws);
  k5_out<<<BB / 256, 256, 0, stream>>>(hT, ws, clsw, clsb, out);
}

// Round 2
// 649.905 us; speedup vs baseline: 1.8024x; 1.8024x over previous
//
#include <hip/hip_runtime.h>
#include <math.h>

#define BB 4096
#define CC 32
#define TT 512
#define NOUTC 16
#define EPSF 1e-5f
#define XS 520   // bf16 row stride: 1040 B = 260 words (16B-aligned, 4-bank rotation)

// ws layout (floats): 0: scale1[32]  32: shift1[32]  64: scale2[32]  96: shift2[32]
// 128: hT[32][4096] (131072)   131200: part[64][4096] (262144)  -> 1.57 MB total

typedef __attribute__((ext_vector_type(16))) float f32x16;
typedef __attribute__((ext_vector_type(4)))  float f32x4;
typedef __attribute__((ext_vector_type(8)))  short short8;

__device__ __forceinline__ unsigned short f2b(float f) {
  unsigned int u = __builtin_bit_cast(unsigned int, f);
  return (unsigned short)((u + 0x7FFFu + ((u >> 16) & 1u)) >> 16);
}
__device__ __forceinline__ float b2f(unsigned short h) {
  unsigned int u = ((unsigned int)h) << 16;
  return __builtin_bit_cast(float, u);
}

// ---------------- kernel 1: conv (direct global reads) + BN1 stat partials ----------------
__global__ __launch_bounds__(256) void k1_stats(const float* __restrict__ de,
    const float* __restrict__ dw, const float* __restrict__ db,
    const float* __restrict__ pw, const float* __restrict__ pwb,
    float* __restrict__ part) {
  __shared__ float pr[4 * 64];
  int tid = threadIdx.x, b = blockIdx.x;
  int w = tid >> 6, lane = tid & 63;
  const float* deb = de + (size_t)b * CC * TT;
  int t0 = tid * 2;
  float x1A[CC], x1B[CC];
#pragma unroll
  for (int c = 0; c < CC; c++) {
    const float* p = deb + c * TT + t0;
    float vm1 = (tid > 0) ? p[-1] : 0.f;
    float v0 = p[0];
    float vp1 = p[1];
    float vp2 = (tid < 255) ? p[2] : 0.f;
    float w0 = dw[c * 3], w1 = dw[c * 3 + 1], w2 = dw[c * 3 + 2], bc = db[c];
    x1A[c] = fmaf(w0, vm1, fmaf(w1, v0, fmaf(w2, vp1, bc)));
    x1B[c] = fmaf(w0, v0, fmaf(w1, vp1, fmaf(w2, vp2, bc)));
  }
#pragma unroll
  for (int o = 0; o < CC; o++) {
    float aA = pwb[o], aB = pwb[o];
#pragma unroll
    for (int c = 0; c < CC; c++) { float pv = pw[o * CC + c]; aA = fmaf(pv, x1A[c], aA); aB = fmaf(pv, x1B[c], aB); }
    float s = aA + aB, q = fmaf(aA, aA, aB * aB);
#pragma unroll
    for (int d = 1; d < 64; d <<= 1) { s += __shfl_xor(s, d); q += __shfl_xor(q, d); }
    if (lane == 0) { pr[w * 64 + o] = s; pr[w * 64 + 32 + o] = q; }
  }
  __syncthreads();
  if (tid < 64) {
    float v = pr[tid] + pr[64 + tid] + pr[128 + tid] + pr[192 + tid];
    part[(size_t)tid * BB + b] = v;
  }
}

// ---------------- kernel 2: finalize BN1 scale/shift ----------------
__global__ void k2_bn1(const float* __restrict__ part, const float* __restrict__ g,
                       const float* __restrict__ bta, float* __restrict__ ws) {
  __shared__ float redS[256], redQ[256];
  int o = blockIdx.x, tid = threadIdx.x;
  const float* ps = part + (size_t)o * BB;
  const float* pq = part + (size_t)(CC + o) * BB;
  float s = 0, q = 0;
  for (int i = tid; i < BB; i += 256) { s += ps[i]; q += pq[i]; }
  redS[tid] = s; redQ[tid] = q;
  __syncthreads();
  for (int k = 128; k > 0; k >>= 1) {
    if (tid < k) { redS[tid] += redS[tid + k]; redQ[tid] += redQ[tid + k]; }
    __syncthreads();
  }
  if (tid == 0) {
    float N = (float)BB * (float)TT;
    float mean = redS[0] / N;
    float var = redQ[0] / N - mean * mean;
    float sc = g[o] / sqrtf(var + EPSF);
    ws[o] = sc;
    ws[32 + o] = bta[o] - mean * sc;
  }
}

// ---------------- kernel 3: per-sample main pipeline (MFMA Gram + Z) ----------------
__global__ __launch_bounds__(256) void k3_main(const float* __restrict__ de,
    const float* __restrict__ dw, const float* __restrict__ db,
    const float* __restrict__ pw, const float* __restrict__ pwb,
    const float* __restrict__ ws, const float* __restrict__ gcw,
    const float* __restrict__ fcw, const float* __restrict__ fcb,
    float* __restrict__ hT) {
  __shared__ __align__(16) unsigned short x_s[CC * XS];     // 33280 B, bf16 x [c][t]
  __shared__ __align__(16) unsigned short gc_s[NOUTC * XS]; // 16640 B, bf16 gc_w^T [o][t]
  __shared__ float gramP[2][CC * CC];                       // 8192 B
  __shared__ float zP[2][CC * NOUTC];                       // 4096 B
  __shared__ float num_s[CC * 33];                          // 4224 B
  __shared__ float muW[4 * CC];
  __shared__ float mu_s[CC];
  __shared__ float inv_s[CC];
  __shared__ float Zi_s[CC * NOUTC];
  __shared__ float g2_s[CC * NOUTC];
  __shared__ float red2[CC * 9];

  int tid = threadIdx.x, b = blockIdx.x;
  int w = tid >> 6, lane = tid & 63;
  const float* deb = de + (size_t)b * CC * TT;

  // stage gc_w^T as bf16 (gcw is [512][16] row-major; read coalesced)
  for (int i = tid; i < TT * NOUTC; i += 256) {
    int t = i >> 4, o = i & 15;
    gc_s[o * XS + t] = f2b(gcw[i]);
  }

  // conv (recompute) + BN1 + relu -> bf16 into LDS; mu from the *rounded* values
  {
    int t0 = tid * 2;
    float x1A[CC], x1B[CC];
#pragma unroll
    for (int c = 0; c < CC; c++) {
      const float* p = deb + c * TT + t0;
      float vm1 = (tid > 0) ? p[-1] : 0.f;
      float v0 = p[0];
      float vp1 = p[1];
      float vp2 = (tid < 255) ? p[2] : 0.f;
      float w0 = dw[c * 3], w1 = dw[c * 3 + 1], w2 = dw[c * 3 + 2], bc = db[c];
      x1A[c] = fmaf(w0, vm1, fmaf(w1, v0, fmaf(w2, vp1, bc)));
      x1B[c] = fmaf(w0, v0, fmaf(w1, vp1, fmaf(w2, vp2, bc)));
    }
#pragma unroll
    for (int o = 0; o < CC; o++) {
      float aA = pwb[o], aB = pwb[o];
#pragma unroll
      for (int c = 0; c < CC; c++) { float pv = pw[o * CC + c]; aA = fmaf(pv, x1A[c], aA); aB = fmaf(pv, x1B[c], aB); }
      float sc = ws[o], sh = ws[32 + o];
      unsigned short hA = f2b(fmaxf(fmaf(aA, sc, sh), 0.f));
      unsigned short hB = f2b(fmaxf(fmaf(aB, sc, sh), 0.f));
      *(unsigned int*)(&x_s[o * XS + t0]) = (unsigned int)hA | ((unsigned int)hB << 16);
      float s = b2f(hA) + b2f(hB);
#pragma unroll
      for (int d = 1; d < 64; d <<= 1) s += __shfl_xor(s, d);
      if (lane == 0) muW[w * CC + o] = s;
    }
  }
  __syncthreads();

  // MFMA: waves 0,1 = Gram halves (32x32x16, A-frag == B-frag); waves 2,3 = Z halves (16x16x32)
  if (w < 2) {
    int m = lane & 31, kh = lane >> 5;
    f32x16 acc;
#pragma unroll
    for (int r = 0; r < 16; r++) acc[r] = 0.f;
    int kbase = w * 256 + kh * 8;
#pragma unroll
    for (int kk = 0; kk < 256; kk += 16) {
      short8 a = *(const short8*)(&x_s[m * XS + kbase + kk]);
      acc = __builtin_amdgcn_mfma_f32_32x32x16_bf16(a, a, acc, 0, 0, 0);
    }
#pragma unroll
    for (int r = 0; r < 16; r++) {
      int row = (r & 3) + 8 * (r >> 2) + 4 * kh;   // C/D: col=lane&31, row per m74/m101
      gramP[w][row * CC + m] = acc[r];
    }
  } else {
    int w2 = w - 2;
    int n16 = lane & 15, q = lane >> 4;
    f32x4 ac0, ac1;
#pragma unroll
    for (int r = 0; r < 4; r++) { ac0[r] = 0.f; ac1[r] = 0.f; }
    int kbase = w2 * 256 + q * 8;
#pragma unroll
    for (int kk = 0; kk < 256; kk += 32) {
      short8 bfr = *(const short8*)(&gc_s[n16 * XS + kbase + kk]);   // B[k][n=o]
      short8 af0 = *(const short8*)(&x_s[n16 * XS + kbase + kk]);    // A[m=c][k], tile 0
      short8 af1 = *(const short8*)(&x_s[(16 + n16) * XS + kbase + kk]); // tile 1
      ac0 = __builtin_amdgcn_mfma_f32_16x16x32_bf16(af0, bfr, ac0, 0, 0, 0);
      ac1 = __builtin_amdgcn_mfma_f32_16x16x32_bf16(af1, bfr, ac1, 0, 0, 0);
    }
#pragma unroll
    for (int r = 0; r < 4; r++) {
      int row = q * 4 + r;                          // C/D: col=lane&15, row=(lane>>4)*4+r
      zP[w2][row * NOUTC + n16] = ac0[r];
      zP[w2][(16 + row) * NOUTC + n16] = ac1[r];
    }
  }
  __syncthreads();
  if (tid < CC) mu_s[tid] = muW[tid] + muW[CC + tid] + muW[2 * CC + tid] + muW[3 * CC + tid];
  __syncthreads();
  // centered Gram: num_c = Sxx - (Sx_n * Sx_m)/T   (cor = num_c / sqrt(diag_n diag_m))
  for (int i = tid; i < CC * CC; i += 256) {
    int n = i >> 5, m = i & 31;
    num_s[n * 33 + m] = gramP[0][i] + gramP[1][i] - mu_s[n] * mu_s[m] * (1.f / (float)TT);
  }
  for (int i = tid; i < CC * NOUTC; i += 256) Zi_s[i] = zP[0][i] + zP[1][i];
  __syncthreads();
  if (tid < CC) inv_s[tid] = rsqrtf(num_s[tid * 33 + tid]);
  __syncthreads();
  // g2[n][o] = relu(inv_n * sum_m num_c[n][m] * inv_m * Z[m][o])
  for (int i = tid; i < CC * NOUTC; i += 256) {
    int n = i >> 4, o = i & 15;
    float s = 0.f;
#pragma unroll
    for (int m = 0; m < CC; m++) s = fmaf(num_s[n * 33 + m] * inv_s[m], Zi_s[m * NOUTC + o], s);
    g2_s[i] = fmaxf(s * inv_s[n], 0.f);
  }
  __syncthreads();
  // fc: h[j] = fcb[j] + sum_i g2[i] * fcw[i][j]
  {
    int j = tid & 31, ch = tid >> 5;
    float p = 0.f;
#pragma unroll
    for (int ii = 0; ii < 64; ii++) {
      int i = ch * 64 + ii;
      p = fmaf(g2_s[i], fcw[i * CC + j], p);
    }
    red2[j * 9 + ch] = p;
  }
  __syncthreads();
  if (tid < CC) {
    float h = fcb[tid];
#pragma unroll
    for (int ch = 0; ch < 8; ch++) h += red2[tid * 9 + ch];
    hT[(size_t)tid * BB + b] = h;
  }
}

// ---------------- kernel 4: BN2 stats ----------------
__global__ void k4_bn2(const float* __restrict__ hT, const float* __restrict__ g,
                       const float* __restrict__ bta, float* __restrict__ ws) {
  __shared__ float redS[256], redQ[256];
  int j = blockIdx.x, tid = threadIdx.x;
  const float* row = hT + (size_t)j * BB;
  float s = 0, q = 0;
  for (int i = tid; i < BB; i += 256) { float v = row[i]; s += v; q = fmaf(v, v, q); }
  redS[tid] = s; redQ[tid] = q;
  __syncthreads();
  for (int k = 128; k > 0; k >>= 1) {
    if (tid < k) { redS[tid] += redS[tid + k]; redQ[tid] += redQ[tid + k]; }
    __syncthreads();
  }
  if (tid == 0) {
    float N = (float)BB;
    float mean = redS[0] / N;
    float var = redQ[0] / N - mean * mean;
    float sc = g[j] / sqrtf(var + EPSF);
    ws[64 + j] = sc;
    ws[96 + j] = bta[j] - mean * sc;
  }
}

// ---------------- kernel 5: BN2 apply + sigmoid + classifier ----------------
__global__ void k5_out(const float* __restrict__ hT, const float* __restrict__ ws,
                       const float* __restrict__ clsw, const float* __restrict__ clsb,
                       float* __restrict__ out) {
  __shared__ float hs[CC * 257];
  int b0 = blockIdx.x * 256, tid = threadIdx.x;
  for (int i = tid; i < CC * 256; i += 256) {
    int j = i >> 8, bb = i & 255;
    float v = fmaf(hT[(size_t)j * BB + b0 + bb], ws[64 + j], ws[96 + j]);
    hs[j * 257 + bb] = 1.f / (1.f + expf(-v));
  }
  __syncthreads();
  float o0 = clsb[0], o1 = clsb[1], o2 = clsb[2], o3 = clsb[3];
#pragma unroll
  for (int j = 0; j < CC; j++) {
    float h = hs[j * 257 + tid];
    o0 = fmaf(h, clsw[j * 4 + 0], o0);
    o1 = fmaf(h, clsw[j * 4 + 1], o1);
    o2 = fmaf(h, clsw[j * 4 + 2], o2);
    o3 = fmaf(h, clsw[j * 4 + 3], o3);
  }
  float4* out4 = reinterpret_cast<float4*>(out);
  out4[b0 + tid] = make_float4(o0, o1, o2, o3);
}

extern "C" void kernel_launch(void* const* d_in, const int* in_sizes, int n_in,
                              void* d_out, int out_size, void* d_ws, size_t ws_size,
                              hipStream_t stream) {
  const float* de   = (const float*)d_in[0];
  const float* dw   = (const float*)d_in[2];
  const float* db_  = (const float*)d_in[3];
  const float* pw   = (const float*)d_in[4];
  const float* pwb  = (const float*)d_in[5];
  const float* bn1g = (const float*)d_in[6];
  const float* bn1b = (const float*)d_in[7];
  const float* gcw  = (const float*)d_in[8];
  const float* fcw  = (const float*)d_in[9];
  const float* fcb  = (const float*)d_in[10];
  const float* bn2g = (const float*)d_in[11];
  const float* bn2b = (const float*)d_in[12];
  const float* clsw = (const float*)d_in[13];
  const float* clsb = (const float*)d_in[14];

  float* ws   = (float*)d_ws;
  float* hT   = ws + 128;
  float* part = ws + 131200;
  float* out  = (float*)d_out;

  k1_stats<<<BB, 256, 0, stream>>>(de, dw, db_, pw, pwb, part);
  k2_bn1<<<CC, 256, 0, stream>>>(part, bn1g, bn1b, ws);
  k3_main<<<BB, 256, 0, stream>>>(de, dw, db_, pw, pwb, ws, gcw, fcw, fcb, hT);
  k4_bn2<<<CC, 256, 0, stream>>>(hT, bn2g, bn2b, ws);
  k5_out<<<BB / 256, 256, 0, stream>>>(hT, ws, clsw, clsb, out);
}

// Round 3
// 512.014 us; speedup vs baseline: 2.2879x; 1.2693x over previous
//
#include <hip/hip_runtime.h>
#include <math.h>

#define BB 4096
#define CC 32
#define TT 512
#define NOUTC 16
#define EPSF 1e-5f
#define XS 520   // bf16 row stride in shorts: 1040 B, 16B-aligned

// ws layout (floats): 0: scale1[32]  32: shift1[32]  64: scale2[32]  96: shift2[32]
// 128: hT[32][4096] (131072)   131200: part[64][4096] (262144)
// 393344: x2h bf16-pairs as u32 [4096][32][256]  (128 MB)  -> need ~129.5 MB total

typedef __attribute__((ext_vector_type(16))) float f32x16;
typedef __attribute__((ext_vector_type(4)))  float f32x4;
typedef __attribute__((ext_vector_type(8)))  short short8;
typedef __attribute__((ext_vector_type(4)))  unsigned int u32x4;
typedef __attribute__((ext_vector_type(4)))  float vf4;
typedef vf4 __attribute__((aligned(4))) vf4u;   // 4B-aligned float4 (dword-aligned dwordx4)

__device__ __forceinline__ unsigned short f2b(float f) {
  unsigned int u = __builtin_bit_cast(unsigned int, f);
  return (unsigned short)((u + 0x7FFFu + ((u >> 16) & 1u)) >> 16);
}
__device__ __forceinline__ float blo(unsigned int u) {
  return __builtin_bit_cast(float, u << 16);
}
__device__ __forceinline__ float bhi(unsigned int u) {
  return __builtin_bit_cast(float, u & 0xFFFF0000u);
}

// depthwise conv for 2 consecutive t-columns per thread (t0 = tid*2), all 32 channels
__device__ __forceinline__ void conv_cols(const float* __restrict__ deb,
    const float* __restrict__ dw, const float* __restrict__ db_,
    int tid, float* x1A, float* x1B) {
  int t0 = tid * 2;
  int off = (tid == 0) ? 0 : ((tid == 255) ? t0 - 2 : t0 - 1);
#pragma unroll
  for (int c = 0; c < CC; c++) {
    vf4u v = *reinterpret_cast<const vf4u*>(deb + c * TT + off);
    float vm1 = (tid == 0) ? 0.f : ((tid == 255) ? v.y : v.x);
    float v0  = (tid == 0) ? v.x : ((tid == 255) ? v.z : v.y);
    float vp1 = (tid == 0) ? v.y : ((tid == 255) ? v.w : v.z);
    float vp2 = (tid == 0) ? v.z : ((tid == 255) ? 0.f : v.w);
    float w0 = dw[c * 3], w1 = dw[c * 3 + 1], w2 = dw[c * 3 + 2], bc = db_[c];
    x1A[c] = fmaf(w0, vm1, fmaf(w1, v0, fmaf(w2, vp1, bc)));
    x1B[c] = fmaf(w0, v0, fmaf(w1, vp1, fmaf(w2, vp2, bc)));
  }
}

// ---------------- kernel 1: conv once -> x2h bf16 + BN1 stat partials ----------------
__global__ __launch_bounds__(256) void k1_stats(const float* __restrict__ de,
    const float* __restrict__ dw, const float* __restrict__ db_,
    const float* __restrict__ pw, const float* __restrict__ pwb,
    float* __restrict__ part, unsigned int* __restrict__ x2h, int useWs) {
  __shared__ float pr[4 * 64];
  int tid = threadIdx.x, b = blockIdx.x;
  int w = tid >> 6, lane = tid & 63;
  const float* deb = de + (size_t)b * CC * TT;
  float x1A[CC], x1B[CC];
  conv_cols(deb, dw, db_, tid, x1A, x1B);
  unsigned int* xw = x2h + (size_t)b * CC * 256;
#pragma unroll
  for (int o = 0; o < CC; o++) {
    float aA = pwb[o], aB = pwb[o];
#pragma unroll
    for (int c = 0; c < CC; c++) { float pv = pw[o * CC + c]; aA = fmaf(pv, x1A[c], aA); aB = fmaf(pv, x1B[c], aB); }
    if (useWs) xw[o * 256 + tid] = (unsigned int)f2b(aA) | ((unsigned int)f2b(aB) << 16);
    float s = aA + aB, q = fmaf(aA, aA, aB * aB);
#pragma unroll
    for (int d = 1; d < 64; d <<= 1) { s += __shfl_xor(s, d); q += __shfl_xor(q, d); }
    if (lane == 0) { pr[w * 64 + o] = s; pr[w * 64 + 32 + o] = q; }
  }
  __syncthreads();
  if (tid < 64) {
    part[(size_t)tid * BB + b] = pr[tid] + pr[64 + tid] + pr[128 + tid] + pr[192 + tid];
  }
}

// ---------------- kernel 2: finalize BN1 scale/shift ----------------
__global__ void k2_bn1(const float* __restrict__ part, const float* __restrict__ g,
                       const float* __restrict__ bta, float* __restrict__ ws) {
  __shared__ float redS[256], redQ[256];
  int o = blockIdx.x, tid = threadIdx.x;
  const float* ps = part + (size_t)o * BB;
  const float* pq = part + (size_t)(CC + o) * BB;
  float s = 0, q = 0;
  for (int i = tid; i < BB; i += 256) { s += ps[i]; q += pq[i]; }
  redS[tid] = s; redQ[tid] = q;
  __syncthreads();
  for (int k = 128; k > 0; k >>= 1) {
    if (tid < k) { redS[tid] += redS[tid + k]; redQ[tid] += redQ[tid + k]; }
    __syncthreads();
  }
  if (tid == 0) {
    float N = (float)BB * (float)TT;
    float mean = redS[0] / N;
    float var = redQ[0] / N - mean * mean;
    float sc = g[o] / sqrtf(var + EPSF);
    ws[o] = sc;
    ws[32 + o] = bta[o] - mean * sc;
  }
}

// ---------------- kernel 3: per-sample main pipeline (MFMA Gram + Z) ----------------
__global__ __launch_bounds__(256) void k3_main(const float* __restrict__ de,
    const float* __restrict__ dw, const float* __restrict__ db_,
    const float* __restrict__ pw, const float* __restrict__ pwb,
    const float* __restrict__ ws, const float* __restrict__ gcw,
    const float* __restrict__ fcw, const float* __restrict__ fcb,
    float* __restrict__ hT, const unsigned int* __restrict__ x2h, int useWs) {
  __shared__ __align__(16) unsigned short x_s[CC * XS];
  __shared__ __align__(16) unsigned short gc_s[NOUTC * XS];
  __shared__ float gramP[2][CC * CC];
  __shared__ float zP[2][CC * NOUTC];
  __shared__ float num_s[CC * 33];
  __shared__ float red16[CC * 8];
  __shared__ float mu_s[CC], inv_s[CC];
  __shared__ float Zi_s[CC * NOUTC];
  __shared__ float g2_s[CC * NOUTC];
  __shared__ float red2[CC * 9];

  int tid = threadIdx.x, b = blockIdx.x;
  int w = tid >> 6, lane = tid & 63;
  int t0 = tid * 2;

  // stage gc_w^T as bf16 (gcw is [512][16] row-major)
  for (int i = tid; i < TT * NOUTC; i += 256) {
    int t = i >> 4, o = i & 15;
    gc_s[o * XS + t] = f2b(gcw[i]);
  }

  if (useWs) {
    // load pre-BN bf16 x2, apply BN1 + relu, round, store to LDS
    const unsigned int* xr = x2h + (size_t)b * CC * 256;
#pragma unroll
    for (int o = 0; o < CC; o++) {
      unsigned int u = xr[o * 256 + tid];
      float sc = ws[o], sh = ws[32 + o];
      unsigned short hA = f2b(fmaxf(fmaf(blo(u), sc, sh), 0.f));
      unsigned short hB = f2b(fmaxf(fmaf(bhi(u), sc, sh), 0.f));
      *(unsigned int*)(&x_s[o * XS + t0]) = (unsigned int)hA | ((unsigned int)hB << 16);
    }
  } else {
    // fallback: recompute conv
    const float* deb = de + (size_t)b * CC * TT;
    float x1A[CC], x1B[CC];
    conv_cols(deb, dw, db_, tid, x1A, x1B);
#pragma unroll
    for (int o = 0; o < CC; o++) {
      float aA = pwb[o], aB = pwb[o];
#pragma unroll
      for (int c = 0; c < CC; c++) { float pv = pw[o * CC + c]; aA = fmaf(pv, x1A[c], aA); aB = fmaf(pv, x1B[c], aB); }
      float sc = ws[o], sh = ws[32 + o];
      unsigned short hA = f2b(fmaxf(fmaf(aA, sc, sh), 0.f));
      unsigned short hB = f2b(fmaxf(fmaf(aB, sc, sh), 0.f));
      *(unsigned int*)(&x_s[o * XS + t0]) = (unsigned int)hA | ((unsigned int)hB << 16);
    }
  }
  __syncthreads();

  // mu partials: strided LDS re-read of x_s (c = tid>>3 row, j = tid&7 chunk of 64 t)
  {
    int c = tid >> 3, j = tid & 7;
    float s = 0.f;
#pragma unroll
    for (int it = 0; it < 8; it++) {
      u32x4 u = *reinterpret_cast<const u32x4*>(&x_s[c * XS + j * 64 + it * 8]);
#pragma unroll
      for (int k = 0; k < 4; k++) s += blo(u[k]) + bhi(u[k]);
    }
    red16[c * 8 + j] = s;
  }

  // MFMA: waves 0,1 = Gram halves (32x32x16, A-frag == B-frag); waves 2,3 = Z halves (16x16x32)
  if (w < 2) {
    int m = lane & 31, kh = lane >> 5;
    f32x16 acc;
#pragma unroll
    for (int r = 0; r < 16; r++) acc[r] = 0.f;
    int kbase = w * 256 + kh * 8;
#pragma unroll
    for (int kk = 0; kk < 256; kk += 16) {
      short8 a = *(const short8*)(&x_s[m * XS + kbase + kk]);
      acc = __builtin_amdgcn_mfma_f32_32x32x16_bf16(a, a, acc, 0, 0, 0);
    }
#pragma unroll
    for (int r = 0; r < 16; r++) {
      int row = (r & 3) + 8 * (r >> 2) + 4 * kh;   // C/D: col=lane&31, row per m74/m101
      gramP[w][row * CC + m] = acc[r];
    }
  } else {
    int w2 = w - 2;
    int n16 = lane & 15, q = lane >> 4;
    f32x4 ac0, ac1;
#pragma unroll
    for (int r = 0; r < 4; r++) { ac0[r] = 0.f; ac1[r] = 0.f; }
    int kbase = w2 * 256 + q * 8;
#pragma unroll
    for (int kk = 0; kk < 256; kk += 32) {
      short8 bfr = *(const short8*)(&gc_s[n16 * XS + kbase + kk]);
      short8 af0 = *(const short8*)(&x_s[n16 * XS + kbase + kk]);
      short8 af1 = *(const short8*)(&x_s[(16 + n16) * XS + kbase + kk]);
      ac0 = __builtin_amdgcn_mfma_f32_16x16x32_bf16(af0, bfr, ac0, 0, 0, 0);
      ac1 = __builtin_amdgcn_mfma_f32_16x16x32_bf16(af1, bfr, ac1, 0, 0, 0);
    }
#pragma unroll
    for (int r = 0; r < 4; r++) {
      int row = q * 4 + r;
      zP[w2][row * NOUTC + n16] = ac0[r];
      zP[w2][(16 + row) * NOUTC + n16] = ac1[r];
    }
  }
  __syncthreads();
  if (tid < CC) {
    float s = 0.f;
#pragma unroll
    for (int j = 0; j < 8; j++) s += red16[tid * 8 + j];
    mu_s[tid] = s;   // Sx per channel
  }
  __syncthreads();
  // centered Gram: num_c = Sxx - Sx_n*Sx_m/T   (cor = num_c / sqrt(diag_n diag_m))
  for (int i = tid; i < CC * CC; i += 256) {
    int n = i >> 5, m = i & 31;
    num_s[n * 33 + m] = gramP[0][i] + gramP[1][i] - mu_s[n] * mu_s[m] * (1.f / (float)TT);
  }
  for (int i = tid; i < CC * NOUTC; i += 256) Zi_s[i] = zP[0][i] + zP[1][i];
  __syncthreads();
  if (tid < CC) inv_s[tid] = rsqrtf(num_s[tid * 33 + tid]);
  __syncthreads();
  // g2[n][o] = relu(inv_n * sum_m num_c[n][m] * inv_m * Z[m][o])
  for (int i = tid; i < CC * NOUTC; i += 256) {
    int n = i >> 4, o = i & 15;
    float s = 0.f;
#pragma unroll
    for (int m = 0; m < CC; m++) s = fmaf(num_s[n * 33 + m] * inv_s[m], Zi_s[m * NOUTC + o], s);
    g2_s[i] = fmaxf(s * inv_s[n], 0.f);
  }
  __syncthreads();
  // fc: h[j] = fcb[j] + sum_i g2[i] * fcw[i][j]
  {
    int j = tid & 31, ch = tid >> 5;
    float p = 0.f;
#pragma unroll
    for (int ii = 0; ii < 64; ii++) {
      int i = ch * 64 + ii;
      p = fmaf(g2_s[i], fcw[i * CC + j], p);
    }
    red2[j * 9 + ch] = p;
  }
  __syncthreads();
  if (tid < CC) {
    float h = fcb[tid];
#pragma unroll
    for (int ch = 0; ch < 8; ch++) h += red2[tid * 9 + ch];
    hT[(size_t)tid * BB + b] = h;
  }
}

// ---------------- kernel 4: BN2 stats ----------------
__global__ void k4_bn2(const float* __restrict__ hT, const float* __restrict__ g,
                       const float* __restrict__ bta, float* __restrict__ ws) {
  __shared__ float redS[256], redQ[256];
  int j = blockIdx.x, tid = threadIdx.x;
  const float* row = hT + (size_t)j * BB;
  float s = 0, q = 0;
  for (int i = tid; i < BB; i += 256) { float v = row[i]; s += v; q = fmaf(v, v, q); }
  redS[tid] = s; redQ[tid] = q;
  __syncthreads();
  for (int k = 128; k > 0; k >>= 1) {
    if (tid < k) { redS[tid] += redS[tid + k]; redQ[tid] += redQ[tid + k]; }
    __syncthreads();
  }
  if (tid == 0) {
    float N = (float)BB;
    float mean = redS[0] / N;
    float var = redQ[0] / N - mean * mean;
    float sc = g[j] / sqrtf(var + EPSF);
    ws[64 + j] = sc;
    ws[96 + j] = bta[j] - mean * sc;
  }
}

// ---------------- kernel 5: BN2 apply + sigmoid + classifier ----------------
__global__ void k5_out(const float* __restrict__ hT, const float* __restrict__ ws,
                       const float* __restrict__ clsw, const float* __restrict__ clsb,
                       float* __restrict__ out) {
  __shared__ float hs[CC * 257];
  int b0 = blockIdx.x * 256, tid = threadIdx.x;
  for (int i = tid; i < CC * 256; i += 256) {
    int j = i >> 8, bb = i & 255;
    float v = fmaf(hT[(size_t)j * BB + b0 + bb], ws[64 + j], ws[96 + j]);
    hs[j * 257 + bb] = 1.f / (1.f + expf(-v));
  }
  __syncthreads();
  float o0 = clsb[0], o1 = clsb[1], o2 = clsb[2], o3 = clsb[3];
#pragma unroll
  for (int j = 0; j < CC; j++) {
    float h = hs[j * 257 + tid];
    o0 = fmaf(h, clsw[j * 4 + 0], o0);
    o1 = fmaf(h, clsw[j * 4 + 1], o1);
    o2 = fmaf(h, clsw[j * 4 + 2], o2);
    o3 = fmaf(h, clsw[j * 4 + 3], o3);
  }
  float4* out4 = reinterpret_cast<float4*>(out);
  out4[b0 + tid] = make_float4(o0, o1, o2, o3);
}

extern "C" void kernel_launch(void* const* d_in, const int* in_sizes, int n_in,
                              void* d_out, int out_size, void* d_ws, size_t ws_size,
                              hipStream_t stream) {
  const float* de   = (const float*)d_in[0];
  const float* dw   = (const float*)d_in[2];
  const float* db_  = (const float*)d_in[3];
  const float* pw   = (const float*)d_in[4];
  const float* pwb  = (const float*)d_in[5];
  const float* bn1g = (const float*)d_in[6];
  const float* bn1b = (const float*)d_in[7];
  const float* gcw  = (const float*)d_in[8];
  const float* fcw  = (const float*)d_in[9];
  const float* fcb  = (const float*)d_in[10];
  const float* bn2g = (const float*)d_in[11];
  const float* bn2b = (const float*)d_in[12];
  const float* clsw = (const float*)d_in[13];
  const float* clsb = (const float*)d_in[14];

  float* ws   = (float*)d_ws;
  float* hT   = ws + 128;
  float* part = ws + 131200;
  unsigned int* x2h = (unsigned int*)(ws + 393344);
  float* out  = (float*)d_out;

  size_t need = 393344ull * 4ull + (size_t)BB * CC * 256 * 4;  // ~129.5 MB
  int useWs = (ws_size >= need) ? 1 : 0;

  k1_stats<<<BB, 256, 0, stream>>>(de, dw, db_, pw, pwb, part, x2h, useWs);
  k2_bn1<<<CC, 256, 0, stream>>>(part, bn1g, bn1b, ws);
  k3_main<<<BB, 256, 0, stream>>>(de, dw, db_, pw, pwb, ws, gcw, fcw, fcb, hT, x2h, useWs);
  k4_bn2<<<CC, 256, 0, stream>>>(hT, bn2g, bn2b, ws);
  k5_out<<<BB / 256, 256, 0, stream>>>(hT, ws, clsw, clsb, out);
}